// Round 3
// baseline (494.561 us; speedup 1.0000x reference)
//
#include <hip/hip_runtime.h>

// MoE RT-DETR FFN on MI355X (gfx950).
// E=6, D=256, H=256, TOP_K=2, ROUTER_H=128, tokens N=8*4096=32768.
// fp32 router (selection exactness) -> per-expert gather -> grouped fp16-MFMA
// GEMM over selected pairs only (3x FLOP cut) -> atomicAdd combine.
//
// Round 3:
//  * router: 64 tok/block, lane=token, wave=32-h slice, uniform weight loads,
//    rotated-float4 LDS x layout (conflict-free transpose reads).
//  * expert: acts-as-B design. D = W^T X^T; weights stream global->VGPR from
//    A-frag-order images (no LDS, no k-loop barriers); LDS holds only the
//    activation B-image (32 KB). Layer boundary: relu+pack -> 16 coalesced
//    ds_write_b64 per wave. 6 barriers/block total.

#define N_TOK 32768
#define E_EXP 6

typedef _Float16 f16x8 __attribute__((ext_vector_type(8)));
typedef float    f32x4 __attribute__((ext_vector_type(4)));
typedef unsigned int u32x4 __attribute__((ext_vector_type(4)));

// ws layout (bytes):
//   [0,256)        counts[6]
//   [256,+768K)    list  [6][32768] int
//   [.. ,+768K)    wlist [6][32768] float
//   [WS_WT,+2.25M) wt fp16 A-frag images [(e*3+l)][kt=8][nt=16][L=64][8]
#define WS_LIST  256
#define WS_WLIST (256 + 786432)
#define WS_WT    (256 + 2 * 786432)

__device__ __forceinline__ unsigned pack_f16x2(float x, float y) {
  unsigned short a = __builtin_bit_cast(unsigned short, (_Float16)x);
  unsigned short b = __builtin_bit_cast(unsigned short, (_Float16)y);
  return (unsigned)a | ((unsigned)b << 16);
}

// ---------------------------------------------------------------------------
// K1: convert expert weights fp32 [E][256][256] (W[k][n], n contiguous) into
// fp16 A-operand fragment images: img[kt][nt][L][j] = W[kt*32+(L>>4)*8+j]
// [nt*16+(L&15)].  One block per (e,l,kt): 144 blocks.
// ---------------------------------------------------------------------------
__global__ __launch_bounds__(256) void convert_w_kernel(
    const float* __restrict__ w1, const float* __restrict__ w2,
    const float* __restrict__ w3, _Float16* __restrict__ wt) {
  __shared__ __align__(16) float xs[32 * 256];
  int blk = blockIdx.x;               // 144 = 6*3*8
  int kt = blk & 7, el = blk >> 3, l = el % 3, e = el / 3;
  const float* W = (l == 0 ? w1 : (l == 1 ? w2 : w3)) +
                   (size_t)e * 65536 + (size_t)kt * 32 * 256;
  int t = threadIdx.x;
  float4* xs4 = (float4*)xs;
  const float4* s4 = (const float4*)W;
  #pragma unroll
  for (int j = 0; j < 8; ++j) xs4[j * 256 + t] = s4[j * 256 + t];
  __syncthreads();
  _Float16* dst = wt + ((size_t)(e * 3 + l) * 8 + kt) * 8192;
  #pragma unroll
  for (int si = 0; si < 4; ++si) {
    int S = si * 256 + t;             // slot 0..1023 = nt*64 + L
    int Ls = S & 63;
    int n = ((S >> 6) << 4) + (Ls & 15);
    int qq = Ls >> 4;
    u32x4 pk;
    #pragma unroll
    for (int i = 0; i < 4; ++i) {
      float x = xs[(qq * 8 + 2 * i) * 256 + n];
      float y = xs[(qq * 8 + 2 * i + 1) * 256 + n];
      pk[i] = pack_f16x2(x, y);
    }
    *(u32x4*)(dst + S * 8) = pk;
  }
}

// ---------------------------------------------------------------------------
// K2: router. 256 threads, 64 tokens/block (512 blocks = 2/CU).
// lane t = token; wave wv owns h in [wv*32, wv*32+32). fp32 throughout.
// x staged in LDS with per-row float4 rotation: xs4[t][ (c4+t)&63 ] so both
// the staging write (row-major) and the transposed read (col-major) are
// contiguous-per-wave b128 -> conflict-free.
// ---------------------------------------------------------------------------
__global__ __launch_bounds__(256) void router_kernel(
    const float* __restrict__ feat, const float* __restrict__ rw1,
    const float* __restrict__ rb1, const float* __restrict__ rw2,
    const float* __restrict__ rb2, int* __restrict__ counts,
    int* __restrict__ list, float* __restrict__ wlist) {
  __shared__ __align__(16) float xs[64 * 256];   // 64 KB
  __shared__ float plg[4 * 64 * 6];              // 6 KB partial logits
  __shared__ int   lcnt[E_EXP];
  __shared__ int   gbase[E_EXP];
  int tid  = threadIdx.x;
  int t    = tid & 63;
  int tok0 = blockIdx.x * 64;
  int hb   = __builtin_amdgcn_readfirstlane((tid >> 6) * 32);

  // stage x: rotated-float4 layout
  float4* xs4 = (float4*)xs;
  const float4* src = (const float4*)(feat + (size_t)tok0 * 256);
  #pragma unroll
  for (int j = 0; j < 16; ++j) {
    int g = j * 256 + tid;            // float4 index; per wave: row fixed
    int row = g >> 6, c4 = g & 63;
    xs4[row * 64 + ((c4 + row) & 63)] = src[g];
  }
  if (tid < E_EXP) lcnt[tid] = 0;
  __syncthreads();

  // layer 1: acc[idx] = x[t] . rw1[:, hb+idx] (idx 0..31)
  float acc[32];
  #pragma unroll
  for (int i = 0; i < 32; ++i) acc[i] = rb1[hb + i];
  for (int c4 = 0; c4 < 64; ++c4) {
    float4 xv = xs4[t * 64 + ((c4 + t) & 63)];
    const float* wk = rw1 + c4 * 4 * 128 + hb;
    #pragma unroll
    for (int kk = 0; kk < 4; ++kk) {
      float xk = (kk == 0) ? xv.x : (kk == 1) ? xv.y : (kk == 2) ? xv.z : xv.w;
      const float4* w4p = (const float4*)(wk + kk * 128);
      #pragma unroll
      for (int jj = 0; jj < 8; ++jj) {
        float4 w4 = w4p[jj];
        acc[jj * 4 + 0] = fmaf(xk, w4.x, acc[jj * 4 + 0]);
        acc[jj * 4 + 1] = fmaf(xk, w4.y, acc[jj * 4 + 1]);
        acc[jj * 4 + 2] = fmaf(xk, w4.z, acc[jj * 4 + 2]);
        acc[jj * 4 + 3] = fmaf(xk, w4.w, acc[jj * 4 + 3]);
      }
    }
  }

  // layer 2 partials over this wave's 32 h
  float plog[E_EXP] = {0.f, 0.f, 0.f, 0.f, 0.f, 0.f};
  #pragma unroll
  for (int j = 0; j < 32; ++j) {
    float r = fmaxf(acc[j], 0.f);
    const float* w2r = rw2 + (hb + j) * E_EXP;
    #pragma unroll
    for (int e2 = 0; e2 < E_EXP; ++e2)
      plog[e2] = fmaf(r, w2r[e2], plog[e2]);
  }
  {
    float* pp = plg + ((tid >> 6) * 64 + t) * E_EXP;
    #pragma unroll
    for (int e2 = 0; e2 < E_EXP; ++e2) pp[e2] = plog[e2];
  }
  __syncthreads();

  // wave 0: combine, softmax, top-2, renorm, block-aggregated scatter
  int sel0 = 0, sel1 = 0, loc0 = 0, loc1 = 0, token = 0;
  float sw0 = 0.f, sw1 = 0.f;
  if (tid < 64) {
    token = tok0 + tid;
    float p[E_EXP];
    float mx = -1e30f;
    #pragma unroll
    for (int i = 0; i < E_EXP; ++i) {
      p[i] = rb2[i] + plg[(0 * 64 + tid) * E_EXP + i]
                    + plg[(1 * 64 + tid) * E_EXP + i]
                    + plg[(2 * 64 + tid) * E_EXP + i]
                    + plg[(3 * 64 + tid) * E_EXP + i];
      mx = fmaxf(mx, p[i]);
    }
    float sum = 0.f;
    #pragma unroll
    for (int i = 0; i < E_EXP; ++i) { p[i] = expf(p[i] - mx); sum += p[i]; }
    float inv = 1.f / sum;
    #pragma unroll
    for (int i = 0; i < E_EXP; ++i) p[i] *= inv;
    float b1v = p[0]; sel0 = 0;
    #pragma unroll
    for (int i = 1; i < E_EXP; ++i) if (p[i] > b1v) { b1v = p[i]; sel0 = i; }
    float b2v = -1.f; sel1 = 0;
    #pragma unroll
    for (int i = 0; i < E_EXP; ++i)
      if (i != sel0 && p[i] > b2v) { b2v = p[i]; sel1 = i; }
    float r = expf(b2v - b1v);        // softmax over the two top probabilities
    sw0 = 1.f / (1.f + r);
    sw1 = r / (1.f + r);
    loc0 = atomicAdd(&lcnt[sel0], 1);
    loc1 = atomicAdd(&lcnt[sel1], 1);
  }
  __syncthreads();
  if (tid < E_EXP) gbase[tid] = atomicAdd(&counts[tid], lcnt[tid]);
  __syncthreads();
  if (tid < 64) {
    int p0 = gbase[sel0] + loc0;
    list[sel0 * N_TOK + p0]  = token;
    wlist[sel0 * N_TOK + p0] = sw0;
    int p1 = gbase[sel1] + loc1;
    list[sel1 * N_TOK + p1]  = token;
    wlist[sel1 * N_TOK + p1] = sw1;
  }
}

// ---------------------------------------------------------------------------
// K3: grouped GEMM, acts-as-B. Block = 256 thr (4 waves), M=64 tokens.
// D[n][m] = sum_k W^T[n][k] X^T[k][m]; wave wv owns n in [wv*64, +64) as a
// 4x4 tile grid of 16x16x32 f16 MFMA. A (weights) stream global->VGPR with
// 1-step register prefetch; B (acts) in a single 32 KB LDS frag image,
// rewritten in place at layer boundaries (coalesced b64 stores).
// ---------------------------------------------------------------------------
__global__ __launch_bounds__(256, 2) void expert_kernel(
    const float* __restrict__ feat, const _Float16* __restrict__ wt,
    const float* __restrict__ eb1, const float* __restrict__ eb2,
    const float* __restrict__ eb3, const int* __restrict__ counts,
    const int* __restrict__ list, const float* __restrict__ wlist,
    float* __restrict__ out) {
  __shared__ __align__(16) _Float16 Bimg[8 * 4 * 64 * 8];  // 32 KB
  __shared__ int   toks[64];
  __shared__ float wgts[64];

  int e    = blockIdx.y;
  int tile = blockIdx.x;
  int cnt  = counts[e];
  int base = tile * 64;
  if (base >= cnt) return;

  int tid = threadIdx.x;
  int wv = tid >> 6, L = tid & 63, m = L & 15, q = L >> 4;

  if (tid < 64) {
    int idx = base + tid;
    int tk = 0; float w = 0.f;
    if (idx < cnt) { tk = list[e * N_TOK + idx]; w = wlist[e * N_TOK + idx]; }
    toks[tid] = tk;
    wgts[tid] = w;                    // w==0 pad rows add exact 0
  }

  const _Float16* aimg = wt + (size_t)(e * 3) * 65536;
  // A frag for (layer l, kstep kt, n-tile rt): per-lane 16 B, coalesced 1 KB
  auto ldA = [&](int l, int kt, int rt) -> f16x8 {
    return *(const f16x8*)(aimg + (size_t)l * 65536 +
                           ((kt * 16 + wv * 4 + rt) * 64 + L) * 8);
  };
  f16x8 ac[4];
  #pragma unroll
  for (int rt = 0; rt < 4; ++rt) ac[rt] = ldA(0, 0, rt);

  __syncthreads();                    // toks/wgts visible

  // stage B layer-1: gather token rows fp32 -> fp16 frag order (b128, coalesced)
  {
    int mm = tid >> 2, gg = tid & 3;
    const float* srcr = feat + (size_t)toks[mm] * 256;
    #pragma unroll
    for (int i = 0; i < 8; ++i) {
      int k0 = (i * 4 + gg) * 8;
      float4 va = *(const float4*)(srcr + k0);
      float4 vb = *(const float4*)(srcr + k0 + 4);
      u32x4 pk;
      pk[0] = pack_f16x2(va.x, va.y);
      pk[1] = pack_f16x2(va.z, va.w);
      pk[2] = pack_f16x2(vb.x, vb.y);
      pk[3] = pack_f16x2(vb.z, vb.w);
      int off = ((i * 4 + (mm >> 4)) * 64 + gg * 16 + (mm & 15)) * 8;
      *(u32x4*)(Bimg + off) = pk;
    }
  }
  __syncthreads();

  const float* bias[3] = {eb1 + e * 256, eb2 + e * 256, eb3 + e * 256};
  f32x4 acc[4][4];                    // [rt][ct]

  #pragma unroll
  for (int l = 0; l < 3; ++l) {
    #pragma unroll
    for (int rt = 0; rt < 4; ++rt) {
      float4 bv = *(const float4*)(bias[l] + wv * 64 + rt * 16 + q * 4);
      #pragma unroll
      for (int ct = 0; ct < 4; ++ct) {
        acc[rt][ct][0] = bv.x; acc[rt][ct][1] = bv.y;
        acc[rt][ct][2] = bv.z; acc[rt][ct][3] = bv.w;
      }
    }
    #pragma unroll
    for (int kt = 0; kt < 8; ++kt) {
      f16x8 an[4];
      if (kt < 7) {
        #pragma unroll
        for (int rt = 0; rt < 4; ++rt) an[rt] = ldA(l, kt + 1, rt);
      } else if (l < 2) {
        #pragma unroll
        for (int rt = 0; rt < 4; ++rt) an[rt] = ldA(l + 1, 0, rt);
      }
      f16x8 b[4];
      #pragma unroll
      for (int ct = 0; ct < 4; ++ct)
        b[ct] = *(const f16x8*)(Bimg + ((kt * 4 + ct) * 64 + L) * 8);
      #pragma unroll
      for (int rt = 0; rt < 4; ++rt)
        #pragma unroll
        for (int ct = 0; ct < 4; ++ct)
          acc[rt][ct] = __builtin_amdgcn_mfma_f32_16x16x32_f16(
              ac[rt], b[ct], acc[rt][ct], 0, 0, 0);
      #pragma unroll
      for (int rt = 0; rt < 4; ++rt) ac[rt] = an[rt];
    }
    if (l < 2) {
      __syncthreads();                // all B reads done before overwrite
      // relu + pack -> next-layer B frags: one b64 store per (rt,ct)
      #pragma unroll
      for (int rt = 0; rt < 4; ++rt) {
        int kt2 = wv * 2 + (rt >> 1);
        int hs  = (rt & 1) * 2 + (q >> 1);
        #pragma unroll
        for (int ct = 0; ct < 4; ++ct) {
          uint2 pk;
          pk.x = pack_f16x2(fmaxf(acc[rt][ct][0], 0.f), fmaxf(acc[rt][ct][1], 0.f));
          pk.y = pack_f16x2(fmaxf(acc[rt][ct][2], 0.f), fmaxf(acc[rt][ct][3], 0.f));
          int off = ((kt2 * 4 + ct) * 64 + hs * 16 + m) * 8 + (q & 1) * 4;
          *(uint2*)(Bimg + off) = pk;
        }
      }
      __syncthreads();
    } else {
      #pragma unroll
      for (int ct = 0; ct < 4; ++ct) {
        int   tk = toks[ct * 16 + m];
        float wg = wgts[ct * 16 + m];
        float* op = out + (size_t)tk * 256 + wv * 64 + q * 4;
        #pragma unroll
        for (int rt = 0; rt < 4; ++rt)
          #pragma unroll
          for (int r = 0; r < 4; ++r)
            atomicAdd(op + rt * 16 + r, acc[rt][ct][r] * wg);
      }
    }
  }
}

extern "C" void kernel_launch(void* const* d_in, const int* in_sizes, int n_in,
                              void* d_out, int out_size, void* d_ws, size_t ws_size,
                              hipStream_t stream) {
  const float* feat = (const float*)d_in[0];
  const float* rw1  = (const float*)d_in[1];
  const float* rb1  = (const float*)d_in[2];
  const float* rw2  = (const float*)d_in[3];
  const float* rb2  = (const float*)d_in[4];
  const float* ew1  = (const float*)d_in[5];
  const float* eb1  = (const float*)d_in[6];
  const float* ew2  = (const float*)d_in[7];
  const float* eb2  = (const float*)d_in[8];
  const float* ew3  = (const float*)d_in[9];
  const float* eb3  = (const float*)d_in[10];
  float* out = (float*)d_out;

  char* ws = (char*)d_ws;
  int*      counts = (int*)(ws);
  int*      list   = (int*)(ws + WS_LIST);
  float*    wlist  = (float*)(ws + WS_WLIST);
  _Float16* wt     = (_Float16*)(ws + WS_WT);

  hipMemsetAsync(ws, 0, 256, stream);
  hipMemsetAsync(d_out, 0, (size_t)out_size * sizeof(float), stream);

  convert_w_kernel<<<144, 256, 0, stream>>>(ew1, ew2, ew3, wt);
  router_kernel<<<N_TOK / 64, 256, 0, stream>>>(feat, rw1, rb1, rw2, rb2,
                                                counts, list, wlist);
  expert_kernel<<<dim3(512, E_EXP), 256, 0, stream>>>(
      feat, wt, eb1, eb2, eb3, counts, list, wlist, out);
}

// Round 4
// 256.884 us; speedup vs baseline: 1.9252x; 1.9252x over previous
//
#include <hip/hip_runtime.h>

// MoE RT-DETR FFN on MI355X (gfx950).
// E=6, D=256, H=256, TOP_K=2, ROUTER_H=128, tokens N=8*4096=32768.
// fp32 router (selection exactness) -> per-expert gather -> grouped fp16-MFMA
// GEMM over selected pairs only (3x FLOP cut) -> atomicAdd combine.
//
// Round 4: acts-as-A (coalesced epilogue, v2) + weights-as-B global->VGPR
// streaming (barrier-free k-loop, v3) + natural frag-order A image in LDS
// (single ds_read_b128 feeds) + DPP 4x4 transpose at layer boundaries so the
// writeback is conflict-free ds_write_b64 (VALU pipe pays, LDS pipe idles).
// Flat work-id grid (1030 blocks) replaces the 3072-block early-exit grid.

#define N_TOK 32768
#define E_EXP 6

typedef _Float16 f16x8 __attribute__((ext_vector_type(8)));
typedef float    f32x4 __attribute__((ext_vector_type(4)));
typedef unsigned int u32x4 __attribute__((ext_vector_type(4)));

// ws layout (bytes):
//   [0,256)        counts[6]
//   [256,+768K)    list  [6][32768] int
//   [.. ,+768K)    wlist [6][32768] float
//   [WS_WT,+2.25M) wt fp16 B-frag images [(e*3+l)][kt=8][nt=16][L=64][8]
#define WS_LIST  256
#define WS_WLIST (256 + 786432)
#define WS_WT    (256 + 2 * 786432)

__device__ __forceinline__ unsigned pack_f16x2(float x, float y) {
  unsigned short a = __builtin_bit_cast(unsigned short, (_Float16)x);
  unsigned short b = __builtin_bit_cast(unsigned short, (_Float16)y);
  return (unsigned)a | ((unsigned)b << 16);
}

// ---------------------------------------------------------------------------
// K1: convert expert weights fp32 [E][256][256] (W[k][n], n contiguous) into
// fp16 B-operand fragment images: img[kt][nt][L][j] = W[kt*32+(L>>4)*8+j]
// [nt*16+(L&15)].  One block per (e,l,kt): 144 blocks.
// ---------------------------------------------------------------------------
__global__ __launch_bounds__(256) void convert_w_kernel(
    const float* __restrict__ w1, const float* __restrict__ w2,
    const float* __restrict__ w3, _Float16* __restrict__ wt) {
  __shared__ __align__(16) float xs[32 * 256];
  int blk = blockIdx.x;               // 144 = 6*3*8
  int kt = blk & 7, el = blk >> 3, l = el % 3, e = el / 3;
  const float* W = (l == 0 ? w1 : (l == 1 ? w2 : w3)) +
                   (size_t)e * 65536 + (size_t)kt * 32 * 256;
  int t = threadIdx.x;
  float4* xs4 = (float4*)xs;
  const float4* s4 = (const float4*)W;
  #pragma unroll
  for (int j = 0; j < 8; ++j) xs4[j * 256 + t] = s4[j * 256 + t];
  __syncthreads();
  _Float16* dst = wt + ((size_t)(e * 3 + l) * 8 + kt) * 8192;
  #pragma unroll
  for (int si = 0; si < 4; ++si) {
    int S = si * 256 + t;             // slot 0..1023 = nt*64 + L
    int Ls = S & 63;
    int n = ((S >> 6) << 4) + (Ls & 15);
    int qq = Ls >> 4;
    u32x4 pk;
    #pragma unroll
    for (int i = 0; i < 4; ++i) {
      float x = xs[(qq * 8 + 2 * i) * 256 + n];
      float y = xs[(qq * 8 + 2 * i + 1) * 256 + n];
      pk[i] = pack_f16x2(x, y);
    }
    *(u32x4*)(dst + S * 8) = pk;
  }
}

// ---------------------------------------------------------------------------
// K2: router. 256 threads, 64 tokens/block (512 blocks = 2/CU).
// lane t = token; wave wv owns h in [wv*32, wv*32+32). fp32 throughout.
// ---------------------------------------------------------------------------
__global__ __launch_bounds__(256) void router_kernel(
    const float* __restrict__ feat, const float* __restrict__ rw1,
    const float* __restrict__ rb1, const float* __restrict__ rw2,
    const float* __restrict__ rb2, int* __restrict__ counts,
    int* __restrict__ list, float* __restrict__ wlist) {
  __shared__ __align__(16) float xs[64 * 256];   // 64 KB
  __shared__ float plg[4 * 64 * 6];              // 6 KB partial logits
  __shared__ int   lcnt[E_EXP];
  __shared__ int   gbase[E_EXP];
  int tid  = threadIdx.x;
  int t    = tid & 63;
  int tok0 = blockIdx.x * 64;
  int hb   = __builtin_amdgcn_readfirstlane((tid >> 6) * 32);

  float4* xs4 = (float4*)xs;
  const float4* src = (const float4*)(feat + (size_t)tok0 * 256);
  #pragma unroll
  for (int j = 0; j < 16; ++j) {
    int g = j * 256 + tid;
    int row = g >> 6, c4 = g & 63;
    xs4[row * 64 + ((c4 + row) & 63)] = src[g];
  }
  if (tid < E_EXP) lcnt[tid] = 0;
  __syncthreads();

  float acc[32];
  #pragma unroll
  for (int i = 0; i < 32; ++i) acc[i] = rb1[hb + i];
  for (int c4 = 0; c4 < 64; ++c4) {
    float4 xv = xs4[t * 64 + ((c4 + t) & 63)];
    const float* wk = rw1 + c4 * 4 * 128 + hb;
    #pragma unroll
    for (int kk = 0; kk < 4; ++kk) {
      float xk = (kk == 0) ? xv.x : (kk == 1) ? xv.y : (kk == 2) ? xv.z : xv.w;
      const float4* w4p = (const float4*)(wk + kk * 128);
      #pragma unroll
      for (int jj = 0; jj < 8; ++jj) {
        float4 w4 = w4p[jj];
        acc[jj * 4 + 0] = fmaf(xk, w4.x, acc[jj * 4 + 0]);
        acc[jj * 4 + 1] = fmaf(xk, w4.y, acc[jj * 4 + 1]);
        acc[jj * 4 + 2] = fmaf(xk, w4.z, acc[jj * 4 + 2]);
        acc[jj * 4 + 3] = fmaf(xk, w4.w, acc[jj * 4 + 3]);
      }
    }
  }

  float plog[E_EXP] = {0.f, 0.f, 0.f, 0.f, 0.f, 0.f};
  #pragma unroll
  for (int j = 0; j < 32; ++j) {
    float r = fmaxf(acc[j], 0.f);
    const float* w2r = rw2 + (hb + j) * E_EXP;
    #pragma unroll
    for (int e2 = 0; e2 < E_EXP; ++e2)
      plog[e2] = fmaf(r, w2r[e2], plog[e2]);
  }
  {
    float* pp = plg + ((tid >> 6) * 64 + t) * E_EXP;
    #pragma unroll
    for (int e2 = 0; e2 < E_EXP; ++e2) pp[e2] = plog[e2];
  }
  __syncthreads();

  int sel0 = 0, sel1 = 0, loc0 = 0, loc1 = 0, token = 0;
  float sw0 = 0.f, sw1 = 0.f;
  if (tid < 64) {
    token = tok0 + tid;
    float p[E_EXP];
    float mx = -1e30f;
    #pragma unroll
    for (int i = 0; i < E_EXP; ++i) {
      p[i] = rb2[i] + plg[(0 * 64 + tid) * E_EXP + i]
                    + plg[(1 * 64 + tid) * E_EXP + i]
                    + plg[(2 * 64 + tid) * E_EXP + i]
                    + plg[(3 * 64 + tid) * E_EXP + i];
      mx = fmaxf(mx, p[i]);
    }
    float sum = 0.f;
    #pragma unroll
    for (int i = 0; i < E_EXP; ++i) { p[i] = expf(p[i] - mx); sum += p[i]; }
    float inv = 1.f / sum;
    #pragma unroll
    for (int i = 0; i < E_EXP; ++i) p[i] *= inv;
    float b1v = p[0]; sel0 = 0;
    #pragma unroll
    for (int i = 1; i < E_EXP; ++i) if (p[i] > b1v) { b1v = p[i]; sel0 = i; }
    float b2v = -1.f; sel1 = 0;
    #pragma unroll
    for (int i = 0; i < E_EXP; ++i)
      if (i != sel0 && p[i] > b2v) { b2v = p[i]; sel1 = i; }
    float r = expf(b2v - b1v);        // softmax over the two top probabilities
    sw0 = 1.f / (1.f + r);
    sw1 = r / (1.f + r);
    loc0 = atomicAdd(&lcnt[sel0], 1);
    loc1 = atomicAdd(&lcnt[sel1], 1);
  }
  __syncthreads();
  if (tid < E_EXP) gbase[tid] = atomicAdd(&counts[tid], lcnt[tid]);
  __syncthreads();
  if (tid < 64) {
    int p0 = gbase[sel0] + loc0;
    list[sel0 * N_TOK + p0]  = token;
    wlist[sel0 * N_TOK + p0] = sw0;
    int p1 = gbase[sel1] + loc1;
    list[sel1 * N_TOK + p1]  = token;
    wlist[sel1 * N_TOK + p1] = sw1;
  }
}

// ---------------------------------------------------------------------------
// K3: grouped GEMM, acts-as-A. Block = 256 thr (4 waves), M=64 tokens.
// D[m][n] = sum_k X[m][k] W[k][n]; wave wv owns n in [wv*64,+64) as 4x4 tiles
// of 16x16x32 f16 MFMA. A (acts) in a 32 KB natural frag-order LDS image,
// rewritten in place at layer boundaries via DPP-transpose + b64 stores.
// B (weights) stream global->VGPR (L2-hot, 1-kt register prefetch).
// Epilogue: C rows = tokens -> coalesced scalar fp32 atomics (64B runs).
// ---------------------------------------------------------------------------
__global__ __launch_bounds__(256, 3) void expert_kernel(
    const float* __restrict__ feat, const _Float16* __restrict__ wt,
    const float* __restrict__ eb1, const float* __restrict__ eb2,
    const float* __restrict__ eb3, const int* __restrict__ counts,
    const int* __restrict__ list, const float* __restrict__ wlist,
    float* __restrict__ out) {
  __shared__ __align__(16) _Float16 Ah[16384];  // [kt=8][rt=4][L=64][8]
  __shared__ int   toks[64];
  __shared__ float wgts[64];

  // flat work-id -> (expert e, tile)
  int bid = blockIdx.x;
  int e = 0, tile = 0, cnt = 0, cum = 0;
  #pragma unroll
  for (int i = 0; i < E_EXP; ++i) {
    int ci = counts[i];
    int nt = (ci + 63) >> 6;
    bool hit = (bid >= cum) && (bid < cum + nt);
    if (hit) { e = i; tile = bid - cum; cnt = ci; }
    cum += nt;
  }
  if (bid >= cum) return;
  int base = tile * 64;

  int tid = threadIdx.x;
  int wv = tid >> 6, L = tid & 63, m = L & 15, q = L >> 4;
  int wcol = wv * 64;

  if (tid < 64) {
    int idx = base + tid;
    int tk = 0; float w = 0.f;
    if (idx < cnt) { tk = list[e * N_TOK + idx]; w = wlist[e * N_TOK + idx]; }
    toks[tid] = tk;
    wgts[tid] = w;                    // w==0 pad rows add exact 0
  }
  __syncthreads();

  // stage A (layer-1 acts): gather token rows fp32 -> fp16 natural frag image
  {
    int row = tid >> 2, seg = tid & 3;     // row 0..63, seg covers 64 k
    int rt = row >> 4, mm = row & 15;
    const float* srcr = feat + (size_t)toks[row] * 256 + seg * 64;
    #pragma unroll
    for (int i = 0; i < 8; ++i) {
      int k = seg * 64 + i * 8;
      float4 a = *(const float4*)(srcr + i * 8);
      float4 b = *(const float4*)(srcr + i * 8 + 4);
      u32x4 pk;
      pk[0] = pack_f16x2(a.x, a.y);
      pk[1] = pack_f16x2(a.z, a.w);
      pk[2] = pack_f16x2(b.x, b.y);
      pk[3] = pack_f16x2(b.z, b.w);
      int off = (((k >> 5) * 4 + rt) * 64 + ((k >> 3) & 3) * 16 + mm) * 8;
      *(u32x4*)(Ah + off) = pk;
    }
  }

  // B frag (weights) loader: global, L2-hot across blocks of the same expert
  const _Float16* bimg = wt + (size_t)(e * 3) * 65536;
  auto ldB = [&](int l, int kt, int ct) -> f16x8 {
    return *(const f16x8*)(bimg + (size_t)l * 65536 +
                           ((kt * 16 + wv * 4 + ct) * 64 + L) * 8);
  };
  f16x8 bc[4];
  #pragma unroll
  for (int ct = 0; ct < 4; ++ct) bc[ct] = ldB(0, 0, ct);

  __syncthreads();                    // A image ready

  const float* bias[3] = {eb1 + e * 256, eb2 + e * 256, eb3 + e * 256};
  f32x4 acc[4][4];                    // [rt][ct]; rows rt*16+q*4+r, cols wcol+ct*16+m

  #pragma unroll
  for (int l = 0; l < 3; ++l) {
    #pragma unroll
    for (int ct = 0; ct < 4; ++ct) {
      float bv = bias[l][wcol + ct * 16 + m];
      #pragma unroll
      for (int rt = 0; rt < 4; ++rt) {
        acc[rt][ct][0] = bv; acc[rt][ct][1] = bv;
        acc[rt][ct][2] = bv; acc[rt][ct][3] = bv;
      }
    }
    #pragma unroll
    for (int kt = 0; kt < 8; ++kt) {
      f16x8 bn[4];
      if (kt < 7) {
        #pragma unroll
        for (int ct = 0; ct < 4; ++ct) bn[ct] = ldB(l, kt + 1, ct);
      } else if (l < 2) {
        #pragma unroll
        for (int ct = 0; ct < 4; ++ct) bn[ct] = ldB(l + 1, 0, ct);
      }
      f16x8 af[4];
      #pragma unroll
      for (int rt = 0; rt < 4; ++rt)
        af[rt] = *(const f16x8*)(Ah + ((kt * 4 + rt) * 64 + L) * 8);
      #pragma unroll
      for (int rt = 0; rt < 4; ++rt)
        #pragma unroll
        for (int ct = 0; ct < 4; ++ct)
          acc[rt][ct] = __builtin_amdgcn_mfma_f32_16x16x32_f16(
              af[rt], bc[ct], acc[rt][ct], 0, 0, 0);
      #pragma unroll
      for (int ct = 0; ct < 4; ++ct) bc[ct] = bn[ct];
    }
    if (l < 2) {
      __syncthreads();                // all A reads done before overwrite
      // 4x4 DPP transpose within quads -> lane i holds token row q*4+i with
      // 4 consecutive k -> relu+pack -> conflict-free ds_write_b64.
      int i = m & 3;
      bool s1 = (i & 2) != 0, s2 = (i & 1) != 0;
      #pragma unroll
      for (int rt = 0; rt < 4; ++rt) {
        #pragma unroll
        for (int ct = 0; ct < 4; ++ct) {
          float x0 = acc[rt][ct][0], x1 = acc[rt][ct][1];
          float x2 = acc[rt][ct][2], x3 = acc[rt][ct][3];
          float t0 = __shfl_xor(x2, 2), t1 = __shfl_xor(x3, 2);
          float t2 = __shfl_xor(x0, 2), t3 = __shfl_xor(x1, 2);
          x0 = s1 ? t0 : x0;  x1 = s1 ? t1 : x1;
          x2 = s1 ? x2 : t2;  x3 = s1 ? x3 : t3;
          float u0 = __shfl_xor(x1, 1), u1 = __shfl_xor(x0, 1);
          float u2 = __shfl_xor(x3, 1), u3 = __shfl_xor(x2, 1);
          x0 = s2 ? u0 : x0;  x1 = s2 ? x1 : u1;
          x2 = s2 ? u2 : x2;  x3 = s2 ? x3 : u3;
          uint2 pk;
          pk.x = pack_f16x2(fmaxf(x0, 0.f), fmaxf(x1, 0.f));
          pk.y = pack_f16x2(fmaxf(x2, 0.f), fmaxf(x3, 0.f));
          int n0 = wcol + ct * 16 + (m & ~3);   // k base (4 consecutive)
          int m2 = q * 4 + i;                   // token row within tile rt
          int off = (((n0 >> 5) * 4 + rt) * 64 + ((n0 >> 3) & 3) * 16 + m2) * 8 +
                    (n0 & 7);
          *(uint2*)(Ah + off) = pk;
        }
      }
      __syncthreads();
    } else {
      #pragma unroll
      for (int rt = 0; rt < 4; ++rt) {
        #pragma unroll
        for (int r = 0; r < 4; ++r) {
          int row = rt * 16 + q * 4 + r;
          int   tk = toks[row];
          float wg = wgts[row];
          float* op = out + (size_t)tk * 256 + wcol + m;
          #pragma unroll
          for (int ct = 0; ct < 4; ++ct)
            atomicAdd(op + ct * 16, acc[rt][ct][r] * wg);
        }
      }
    }
  }
}

extern "C" void kernel_launch(void* const* d_in, const int* in_sizes, int n_in,
                              void* d_out, int out_size, void* d_ws, size_t ws_size,
                              hipStream_t stream) {
  const float* feat = (const float*)d_in[0];
  const float* rw1  = (const float*)d_in[1];
  const float* rb1  = (const float*)d_in[2];
  const float* rw2  = (const float*)d_in[3];
  const float* rb2  = (const float*)d_in[4];
  const float* ew1  = (const float*)d_in[5];
  const float* eb1  = (const float*)d_in[6];
  const float* ew2  = (const float*)d_in[7];
  const float* eb2  = (const float*)d_in[8];
  const float* ew3  = (const float*)d_in[9];
  const float* eb3  = (const float*)d_in[10];
  float* out = (float*)d_out;

  char* ws = (char*)d_ws;
  int*      counts = (int*)(ws);
  int*      list   = (int*)(ws + WS_LIST);
  float*    wlist  = (float*)(ws + WS_WLIST);
  _Float16* wt     = (_Float16*)(ws + WS_WT);

  hipMemsetAsync(ws, 0, 256, stream);
  hipMemsetAsync(d_out, 0, (size_t)out_size * sizeof(float), stream);

  convert_w_kernel<<<144, 256, 0, stream>>>(ew1, ew2, ew3, wt);
  router_kernel<<<N_TOK / 64, 256, 0, stream>>>(feat, rw1, rb1, rw2, rb2,
                                                counts, list, wlist);
  // 65536 selections -> <=1029 tiles of 64; 1030 covers any distribution.
  expert_kernel<<<1030, 256, 0, stream>>>(
      feat, wt, eb1, eb2, eb3, counts, list, wlist, out);
}

// Round 5
// 231.462 us; speedup vs baseline: 2.1367x; 1.1098x over previous
//
#include <hip/hip_runtime.h>

// MoE RT-DETR FFN on MI355X (gfx950).
// E=6, D=256, H=256, TOP_K=2, ROUTER_H=128, tokens N=8*4096=32768.
//
// Round 5: PAIR-ROUTED experts — tokens bucketed by unordered expert pair
// {a,b} (15 buckets). One block computes BOTH experts for its 64 tokens and
// writes each output row exactly once with plain f32x4 stores: zero atomics,
// no out memset, no combine pass. Router: v2 structure with LDS reuse
// (xs->rh, 33 KB -> 4 blocks/CU) and rh stride 132 (bank-conflict fix).

#define N_TOK 32768
#define E_EXP 6

typedef _Float16 f16x8 __attribute__((ext_vector_type(8)));
typedef float    f32x4 __attribute__((ext_vector_type(4)));
typedef unsigned int u32x4 __attribute__((ext_vector_type(4)));

// ws layout (bytes):
//   [0,256)        counts[15]
//   [WS_LIST,+1.97M) list [15][32768] int (token)
//   [WS_WA,+1.97M)   wA   [15][32768] float (weight of lower expert)
//   [WS_WB,+1.97M)   wB   [15][32768] float (weight of higher expert)
//   [WS_WT,+2.25M)   wt fp16 B-frag images [(e*3+l)][kt=8][nt=16][L=64][8]
#define WS_LIST 256
#define WS_WA   (WS_LIST + 15 * N_TOK * 4)
#define WS_WB   (WS_WA + 15 * N_TOK * 4)
#define WS_WT   (WS_WB + 15 * N_TOK * 4)

__device__ __forceinline__ unsigned pack_f16x2(float x, float y) {
  unsigned short a = __builtin_bit_cast(unsigned short, (_Float16)x);
  unsigned short b = __builtin_bit_cast(unsigned short, (_Float16)y);
  return (unsigned)a | ((unsigned)b << 16);
}

// ---------------------------------------------------------------------------
// K1: convert expert weights fp32 [E][256][256] (W[k][n], n contiguous) into
// fp16 B-operand fragment images: img[kt][nt][L][j] = W[kt*32+(L>>4)*8+j]
// [nt*16+(L&15)].  One block per (e,l,kt): 144 blocks.
// ---------------------------------------------------------------------------
__global__ __launch_bounds__(256) void convert_w_kernel(
    const float* __restrict__ w1, const float* __restrict__ w2,
    const float* __restrict__ w3, _Float16* __restrict__ wt) {
  __shared__ __align__(16) float xs[32 * 256];
  int blk = blockIdx.x;               // 144 = 6*3*8
  int kt = blk & 7, el = blk >> 3, l = el % 3, e = el / 3;
  const float* W = (l == 0 ? w1 : (l == 1 ? w2 : w3)) +
                   (size_t)e * 65536 + (size_t)kt * 32 * 256;
  int t = threadIdx.x;
  float4* xs4 = (float4*)xs;
  const float4* s4 = (const float4*)W;
  #pragma unroll
  for (int j = 0; j < 8; ++j) xs4[j * 256 + t] = s4[j * 256 + t];
  __syncthreads();
  _Float16* dst = wt + ((size_t)(e * 3 + l) * 8 + kt) * 8192;
  #pragma unroll
  for (int si = 0; si < 4; ++si) {
    int S = si * 256 + t;             // slot 0..1023 = nt*64 + L
    int Ls = S & 63;
    int n = ((S >> 6) << 4) + (Ls & 15);
    int qq = Ls >> 4;
    u32x4 pk;
    #pragma unroll
    for (int i = 0; i < 4; ++i) {
      float x = xs[(qq * 8 + 2 * i) * 256 + n];
      float y = xs[(qq * 8 + 2 * i + 1) * 256 + n];
      pk[i] = pack_f16x2(x, y);
    }
    *(u32x4*)(dst + S * 8) = pk;
  }
}

// ---------------------------------------------------------------------------
// K2: router. 128 threads, 32 tokens/block, 1024 blocks. fp32 (selection
// exactness). thread = hidden unit h; 32 tokens in registers; x via LDS
// broadcast. xs reused as rh (stride 132) -> 33 KB LDS -> 4 blocks/CU.
// Emits pair-bucketed lists: pid = b(b-1)/2+a for pair {a<b}.
// ---------------------------------------------------------------------------
__global__ __launch_bounds__(128) void router_kernel(
    const float* __restrict__ feat, const float* __restrict__ rw1,
    const float* __restrict__ rb1, const float* __restrict__ rw2,
    const float* __restrict__ rb2, int* __restrict__ counts,
    int* __restrict__ list, float* __restrict__ wAo,
    float* __restrict__ wBo) {
  __shared__ __align__(16) float xs[32 * 256];   // 32 KB; reused as rh[32][132]
  __shared__ float lg[32 * 6];
  __shared__ int   lcnt[15];
  __shared__ int   gbase[15];
  int tid  = threadIdx.x;
  int tok0 = blockIdx.x * 32;

  const float4* src = (const float4*)(feat + (size_t)tok0 * 256);
  float4* xs4 = (float4*)xs;
  #pragma unroll
  for (int j = 0; j < 16; ++j) xs4[j * 128 + tid] = src[j * 128 + tid];
  if (tid < 15) lcnt[tid] = 0;
  __syncthreads();

  // layer 1: acc[t] = x[t] . rw1[:,tid] + rb1[tid]
  float acc[32];
  {
    float b = rb1[tid];
    #pragma unroll
    for (int t = 0; t < 32; ++t) acc[t] = b;
  }
  for (int d4 = 0; d4 < 64; ++d4) {
    float w0  = rw1[(d4 * 4 + 0) * 128 + tid];
    float w1v = rw1[(d4 * 4 + 1) * 128 + tid];
    float w2v = rw1[(d4 * 4 + 2) * 128 + tid];
    float w3v = rw1[(d4 * 4 + 3) * 128 + tid];
    #pragma unroll
    for (int t = 0; t < 32; ++t) {
      float4 x = xs4[t * 64 + d4];    // wave-uniform broadcast
      acc[t] = fmaf(x.w, w3v, fmaf(x.z, w2v, fmaf(x.y, w1v, fmaf(x.x, w0, acc[t]))));
    }
  }
  __syncthreads();                    // all xs reads done; reuse as rh
  float* rh = xs;
  #pragma unroll
  for (int t = 0; t < 32; ++t) rh[t * 132 + tid] = fmaxf(acc[t], 0.f);
  __syncthreads();

  // layer 2: logits [32][6]
  for (int it = tid; it < 32 * E_EXP; it += 128) {
    int t = it / E_EXP, ei = it % E_EXP;
    float s = rb2[ei];
    for (int h = 0; h < 128; ++h) s += rh[t * 132 + h] * rw2[h * E_EXP + ei];
    lg[t * E_EXP + ei] = s;
  }
  __syncthreads();

  int pid = 0, loc = 0, token = 0;
  float wa = 0.f, wb = 0.f;
  if (tid < 32) {
    token = tok0 + tid;
    float p[E_EXP];
    float mx = -1e30f;
    #pragma unroll
    for (int i = 0; i < E_EXP; ++i) { p[i] = lg[tid * E_EXP + i]; mx = fmaxf(mx, p[i]); }
    float sum = 0.f;
    #pragma unroll
    for (int i = 0; i < E_EXP; ++i) { p[i] = expf(p[i] - mx); sum += p[i]; }
    float inv = 1.f / sum;
    #pragma unroll
    for (int i = 0; i < E_EXP; ++i) p[i] *= inv;
    float b1v = p[0]; int sel0 = 0;
    #pragma unroll
    for (int i = 1; i < E_EXP; ++i) if (p[i] > b1v) { b1v = p[i]; sel0 = i; }
    float b2v = -1.f; int sel1 = 0;
    #pragma unroll
    for (int i = 0; i < E_EXP; ++i)
      if (i != sel0 && p[i] > b2v) { b2v = p[i]; sel1 = i; }
    float r = expf(b2v - b1v);        // softmax over the two top probabilities
    float sw0 = 1.f / (1.f + r);
    float sw1 = r / (1.f + r);
    int a  = min(sel0, sel1), b = max(sel0, sel1);
    wa = (sel0 < sel1) ? sw0 : sw1;   // weight of lower-index expert
    wb = (sel0 < sel1) ? sw1 : sw0;
    pid = b * (b - 1) / 2 + a;
    loc = atomicAdd(&lcnt[pid], 1);
  }
  __syncthreads();
  if (tid < 15) gbase[tid] = atomicAdd(&counts[tid], lcnt[tid]);
  __syncthreads();
  if (tid < 32) {
    int p0 = gbase[pid] + loc;
    list[pid * N_TOK + p0] = token;
    wAo[pid * N_TOK + p0] = wa;
    wBo[pid * N_TOK + p0] = wb;
  }
}

// ---------------------------------------------------------------------------
// K3: pair-fused grouped GEMM. Block = 256 thr (4 waves), 64 tokens, one
// expert PAIR. Two passes (expert lo, hi) over the v4 k-loop (acts-as-A LDS
// image, weights global->VGPR, DPP-transpose layer boundaries). Pass-A
// result held weighted in registers; pass-B combines; output rows stored
// once with predicated f32x4 plain stores. No atomics anywhere.
// ---------------------------------------------------------------------------
__global__ __launch_bounds__(256) void expert_kernel(
    const float* __restrict__ feat, const _Float16* __restrict__ wt,
    const float* __restrict__ eb1, const float* __restrict__ eb2,
    const float* __restrict__ eb3, const int* __restrict__ counts,
    const int* __restrict__ list, const float* __restrict__ wAo,
    const float* __restrict__ wBo, float* __restrict__ out) {
  __shared__ __align__(16) _Float16 Ah[16384];  // [kt=8][rt=4][L=64][8]
  __shared__ int   toks[64];
  __shared__ float wgA[64], wgB[64];

  const int loT[15] = {0,0,1,0,1,2,0,1,2,3,0,1,2,3,4};
  const int hiT[15] = {1,2,2,3,3,3,4,4,4,4,5,5,5,5,5};

  // flat work-id -> (pair pid, tile)
  int bid = blockIdx.x;
  int pid = 0, tile = 0, cnt = 0, cum = 0;
  #pragma unroll
  for (int i = 0; i < 15; ++i) {
    int ci = counts[i];
    int nt = (ci + 63) >> 6;
    bool hit = (bid >= cum) && (bid < cum + nt);
    if (hit) { pid = i; tile = bid - cum; cnt = ci; }
    cum += nt;
  }
  if (bid >= cum) return;
  int base = tile * 64;
  int eLo = loT[pid], eHi = hiT[pid];

  int tid = threadIdx.x;
  int wv = tid >> 6, L = tid & 63, m = L & 15, q = L >> 4;
  int wcol = wv * 64;

  if (tid < 64) {
    int idx = base + tid;
    int tk = 0; float a = 0.f, b = 0.f;
    if (idx < cnt) {
      tk = list[pid * N_TOK + idx];
      a  = wAo[pid * N_TOK + idx];
      b  = wBo[pid * N_TOK + idx];
    }
    toks[tid] = tk; wgA[tid] = a; wgB[tid] = b;
  }
  __syncthreads();

  f32x4 acc[4][4], accS[4][4];

  #pragma unroll
  for (int pass = 0; pass < 2; ++pass) {
    int e = pass ? eHi : eLo;
    if (pass) __syncthreads();          // pass-0 layer-3 A reads done

    // stage A (acts): gather token rows fp32 -> fp16 natural frag image
    {
      int row = tid >> 2, seg = tid & 3;
      int rt = row >> 4, mm = row & 15;
      const float* srcr = feat + (size_t)toks[row] * 256 + seg * 64;
      #pragma unroll
      for (int i = 0; i < 8; ++i) {
        int k = seg * 64 + i * 8;
        float4 a = *(const float4*)(srcr + i * 8);
        float4 b = *(const float4*)(srcr + i * 8 + 4);
        u32x4 pk;
        pk[0] = pack_f16x2(a.x, a.y);
        pk[1] = pack_f16x2(a.z, a.w);
        pk[2] = pack_f16x2(b.x, b.y);
        pk[3] = pack_f16x2(b.z, b.w);
        int off = (((k >> 5) * 4 + rt) * 64 + ((k >> 3) & 3) * 16 + mm) * 8;
        *(u32x4*)(Ah + off) = pk;
      }
    }

    const _Float16* bimg = wt + (size_t)(e * 3) * 65536;
    auto ldB = [&](int l, int kt, int ct) -> f16x8 {
      return *(const f16x8*)(bimg + (size_t)l * 65536 +
                             ((kt * 16 + wv * 4 + ct) * 64 + L) * 8);
    };
    f16x8 bc[4];
    #pragma unroll
    for (int ct = 0; ct < 4; ++ct) bc[ct] = ldB(0, 0, ct);
    __syncthreads();                    // A image ready

    const float* bias[3] = {eb1 + e * 256, eb2 + e * 256, eb3 + e * 256};

    #pragma unroll
    for (int l = 0; l < 3; ++l) {
      #pragma unroll
      for (int ct = 0; ct < 4; ++ct) {
        float bv = bias[l][wcol + ct * 16 + m];
        #pragma unroll
        for (int rt = 0; rt < 4; ++rt) {
          acc[rt][ct][0] = bv; acc[rt][ct][1] = bv;
          acc[rt][ct][2] = bv; acc[rt][ct][3] = bv;
        }
      }
      #pragma unroll
      for (int kt = 0; kt < 8; ++kt) {
        f16x8 bn[4];
        if (kt < 7) {
          #pragma unroll
          for (int ct = 0; ct < 4; ++ct) bn[ct] = ldB(l, kt + 1, ct);
        } else if (l < 2) {
          #pragma unroll
          for (int ct = 0; ct < 4; ++ct) bn[ct] = ldB(l + 1, 0, ct);
        }
        f16x8 af[4];
        #pragma unroll
        for (int rt = 0; rt < 4; ++rt)
          af[rt] = *(const f16x8*)(Ah + ((kt * 4 + rt) * 64 + L) * 8);
        #pragma unroll
        for (int rt = 0; rt < 4; ++rt)
          #pragma unroll
          for (int ct = 0; ct < 4; ++ct)
            acc[rt][ct] = __builtin_amdgcn_mfma_f32_16x16x32_f16(
                af[rt], bc[ct], acc[rt][ct], 0, 0, 0);
        #pragma unroll
        for (int ct = 0; ct < 4; ++ct) bc[ct] = bn[ct];
      }
      if (l < 2) {
        __syncthreads();                // all A reads done before overwrite
        int i = m & 3;
        bool s1 = (i & 2) != 0, s2 = (i & 1) != 0;
        #pragma unroll
        for (int rt = 0; rt < 4; ++rt) {
          #pragma unroll
          for (int ct = 0; ct < 4; ++ct) {
            float x0 = acc[rt][ct][0], x1 = acc[rt][ct][1];
            float x2 = acc[rt][ct][2], x3 = acc[rt][ct][3];
            float t0 = __shfl_xor(x2, 2), t1 = __shfl_xor(x3, 2);
            float t2 = __shfl_xor(x0, 2), t3 = __shfl_xor(x1, 2);
            x0 = s1 ? t0 : x0;  x1 = s1 ? t1 : x1;
            x2 = s1 ? x2 : t2;  x3 = s1 ? x3 : t3;
            float u0 = __shfl_xor(x1, 1), u1 = __shfl_xor(x0, 1);
            float u2 = __shfl_xor(x3, 1), u3 = __shfl_xor(x2, 1);
            x0 = s2 ? u0 : x0;  x1 = s2 ? x1 : u1;
            x2 = s2 ? u2 : x2;  x3 = s2 ? x3 : u3;
            uint2 pk;
            pk.x = pack_f16x2(fmaxf(x0, 0.f), fmaxf(x1, 0.f));
            pk.y = pack_f16x2(fmaxf(x2, 0.f), fmaxf(x3, 0.f));
            int n0 = wcol + ct * 16 + (m & ~3);
            int m2 = q * 4 + i;
            int off = (((n0 >> 5) * 4 + rt) * 64 + ((n0 >> 3) & 3) * 16 + m2) * 8 +
                      (n0 & 7);
            *(uint2*)(Ah + off) = pk;
          }
        }
        __syncthreads();
      }
    }

    // combine weighted results
    if (pass == 0) {
      #pragma unroll
      for (int rt = 0; rt < 4; ++rt)
        #pragma unroll
        for (int r = 0; r < 4; ++r) {
          float wa = wgA[rt * 16 + q * 4 + r];
          #pragma unroll
          for (int ct = 0; ct < 4; ++ct)
            accS[rt][ct][r] = acc[rt][ct][r] * wa;
        }
    } else {
      #pragma unroll
      for (int rt = 0; rt < 4; ++rt)
        #pragma unroll
        for (int r = 0; r < 4; ++r) {
          float wb = wgB[rt * 16 + q * 4 + r];
          #pragma unroll
          for (int ct = 0; ct < 4; ++ct)
            acc[rt][ct][r] = accS[rt][ct][r] + acc[rt][ct][r] * wb;
        }
    }
  }

  // final DPP transpose + predicated f32x4 plain stores (each row once)
  {
    int i = m & 3;
    bool s1 = (i & 2) != 0, s2 = (i & 1) != 0;
    #pragma unroll
    for (int rt = 0; rt < 4; ++rt) {
      int row = rt * 16 + q * 4 + i;
      bool valid = (base + row) < cnt;
      #pragma unroll
      for (int ct = 0; ct < 4; ++ct) {
        float x0 = acc[rt][ct][0], x1 = acc[rt][ct][1];
        float x2 = acc[rt][ct][2], x3 = acc[rt][ct][3];
        float t0 = __shfl_xor(x2, 2), t1 = __shfl_xor(x3, 2);
        float t2 = __shfl_xor(x0, 2), t3 = __shfl_xor(x1, 2);
        x0 = s1 ? t0 : x0;  x1 = s1 ? t1 : x1;
        x2 = s1 ? x2 : t2;  x3 = s1 ? x3 : t3;
        float u0 = __shfl_xor(x1, 1), u1 = __shfl_xor(x0, 1);
        float u2 = __shfl_xor(x3, 1), u3 = __shfl_xor(x2, 1);
        x0 = s2 ? u0 : x0;  x1 = s2 ? x1 : u1;
        x2 = s2 ? u2 : x2;  x3 = s2 ? x3 : u3;
        if (valid) {
          float4 v = make_float4(x0, x1, x2, x3);
          *(float4*)(out + (size_t)toks[row] * 256 + wcol + ct * 16 + (m & ~3)) = v;
        }
      }
    }
  }
}

extern "C" void kernel_launch(void* const* d_in, const int* in_sizes, int n_in,
                              void* d_out, int out_size, void* d_ws, size_t ws_size,
                              hipStream_t stream) {
  const float* feat = (const float*)d_in[0];
  const float* rw1  = (const float*)d_in[1];
  const float* rb1  = (const float*)d_in[2];
  const float* rw2  = (const float*)d_in[3];
  const float* rb2  = (const float*)d_in[4];
  const float* ew1  = (const float*)d_in[5];
  const float* eb1  = (const float*)d_in[6];
  const float* ew2  = (const float*)d_in[7];
  const float* eb2  = (const float*)d_in[8];
  const float* ew3  = (const float*)d_in[9];
  const float* eb3  = (const float*)d_in[10];
  float* out = (float*)d_out;

  char* ws = (char*)d_ws;
  int*      counts = (int*)(ws);
  int*      list   = (int*)(ws + WS_LIST);
  float*    wAo    = (float*)(ws + WS_WA);
  float*    wBo    = (float*)(ws + WS_WB);
  _Float16* wt     = (_Float16*)(ws + WS_WT);

  hipMemsetAsync(ws, 0, 256, stream);   // counts only; out fully overwritten

  convert_w_kernel<<<144, 256, 0, stream>>>(ew1, ew2, ew3, wt);
  router_kernel<<<N_TOK / 32, 128, 0, stream>>>(feat, rw1, rb1, rw2, rb2,
                                                counts, list, wAo, wBo);
  // 32768 tokens -> <=512 full tiles + <=15 ragged: 527 blocks covers all.
  expert_kernel<<<527, 256, 0, stream>>>(
      feat, wt, eb1, eb2, eb3, counts, list, wAo, wBo, out);
}

// Round 7
// 186.400 us; speedup vs baseline: 2.6532x; 1.2417x over previous
//
#include <hip/hip_runtime.h>

// MoE RT-DETR FFN on MI355X (gfx950).
// E=6, D=256, H=256, TOP_K=2, ROUTER_H=128, tokens N=8*4096=32768.
//
// Round 7 = round 6 with the router LDS overflow fixed (split A-images are
// 32 KB EACH: smem union is now 64 KB; rh reuses it after the k-loop).
//  * router layer-1 via SPLIT-FP16 MFMA (x=xh+2^-11*xl, w=wh+2^-11*wl; acc_hi
//    = xh*wh, acc_mid = xh*wl + xl*wh, logits = acc_hi + acc_mid/2048 ->
//    fp32-grade at MFMA rate). Layer-2 + softmax + top-2 in fp32 VALU.
//  * expert: M=32 tiles (grid 1039 -> ~4 blocks/CU) + depth-2 B prefetch over
//    a flat 48-step (pass,layer,kt) schedule. Pair-routed, zero atomics.
//  * counts zeroed inside convert kernel; wb = 1-wa; 3 dispatches total.

#define N_TOK 32768
#define E_EXP 6

typedef _Float16 f16x8 __attribute__((ext_vector_type(8)));
typedef float    f32x4 __attribute__((ext_vector_type(4)));
typedef unsigned int u32x4 __attribute__((ext_vector_type(4)));

// ws layout (bytes):
//   [0,256)           counts[15]
//   [WS_LIST,+1.97M)  list [15][32768] int
//   [WS_WA,+1.97M)    wA   [15][32768] float (weight of lower expert; wb=1-wa)
//   [WS_WT,+2.25M)    wt fp16 expert B-frag images [(e*3+l)][kt8][nt16][64][8]
//   [WS_R1H,+128K)    rw1 hi fp16 B-frag image [kt8][nt8][64][8]
//   [WS_R1L,+128K)    rw1 lo (x2048) fp16 image, same layout
#define WS_LIST 256
#define WS_WA   (WS_LIST + 15 * N_TOK * 4)
#define WS_WT   (WS_WA + 15 * N_TOK * 4)
#define WS_R1H  (WS_WT + 2359296)
#define WS_R1L  (WS_R1H + 131072)

__device__ __forceinline__ unsigned pack_f16x2(float x, float y) {
  unsigned short a = __builtin_bit_cast(unsigned short, (_Float16)x);
  unsigned short b = __builtin_bit_cast(unsigned short, (_Float16)y);
  return (unsigned)a | ((unsigned)b << 16);
}

// split pair: hi = fp16(x); lo = fp16((x-hi)*2048)
__device__ __forceinline__ void split_pair(float x, float y,
                                           unsigned& hi, unsigned& lo) {
  _Float16 xh = (_Float16)x, yh = (_Float16)y;
  float xl = (x - (float)xh) * 2048.f, yl = (y - (float)yh) * 2048.f;
  hi = (unsigned)__builtin_bit_cast(unsigned short, xh) |
       ((unsigned)__builtin_bit_cast(unsigned short, yh) << 16);
  lo = pack_f16x2(xl, yl);
}

// ---------------------------------------------------------------------------
// K1: blocks 0..143: expert weights fp32 [E][256][256] -> fp16 B-frag images
//     img[kt][nt][L][j] = W[kt*32+(L>>4)*8+j][nt*16+(L&15)].
// blocks 144..151: router w1 [256][128] -> hi/lo split B-frag images (1 kt ea).
// block 0 also zeroes counts[15].
// ---------------------------------------------------------------------------
__global__ __launch_bounds__(256) void convert_w_kernel(
    const float* __restrict__ w1, const float* __restrict__ w2,
    const float* __restrict__ w3, const float* __restrict__ rw1,
    _Float16* __restrict__ wt, _Float16* __restrict__ r1h,
    _Float16* __restrict__ r1l, int* __restrict__ counts) {
  __shared__ __align__(16) float xs[32 * 256];
  int blk = blockIdx.x;
  int t = threadIdx.x;
  if (blk == 0 && t < 16) counts[t] = 0;
  float4* xs4 = (float4*)xs;
  if (blk < 144) {
    int kt = blk & 7, el = blk >> 3, l = el % 3, e = el / 3;
    const float* W = (l == 0 ? w1 : (l == 1 ? w2 : w3)) +
                     (size_t)e * 65536 + (size_t)kt * 32 * 256;
    const float4* s4 = (const float4*)W;
    #pragma unroll
    for (int j = 0; j < 8; ++j) xs4[j * 256 + t] = s4[j * 256 + t];
    __syncthreads();
    _Float16* dst = wt + ((size_t)(e * 3 + l) * 8 + kt) * 8192;
    #pragma unroll
    for (int si = 0; si < 4; ++si) {
      int S = si * 256 + t;             // slot = nt*64 + L
      int Ls = S & 63;
      int n = ((S >> 6) << 4) + (Ls & 15);
      int qq = Ls >> 4;
      u32x4 pk;
      #pragma unroll
      for (int i = 0; i < 4; ++i) {
        float x = xs[(qq * 8 + 2 * i) * 256 + n];
        float y = xs[(qq * 8 + 2 * i + 1) * 256 + n];
        pk[i] = pack_f16x2(x, y);
      }
      *(u32x4*)(dst + S * 8) = pk;
    }
  } else {
    int kt = blk - 144;                 // 0..7
    const float4* s4 = (const float4*)(rw1 + (size_t)kt * 32 * 128);
    #pragma unroll
    for (int j = 0; j < 4; ++j) xs4[j * 256 + t] = s4[j * 256 + t];
    __syncthreads();
    #pragma unroll
    for (int si = 0; si < 2; ++si) {
      int S = si * 256 + t;             // slot = nt*64 + L (512 slots)
      int Ls = S & 63;
      int n = ((S >> 6) << 4) + (Ls & 15);
      int qq = Ls >> 4;
      u32x4 ph, pl;
      #pragma unroll
      for (int i = 0; i < 4; ++i) {
        float x = xs[(qq * 8 + 2 * i) * 128 + n];
        float y = xs[(qq * 8 + 2 * i + 1) * 128 + n];
        unsigned hi, lo;
        split_pair(x, y, hi, lo);
        ph[i] = hi; pl[i] = lo;
      }
      size_t off = (size_t)kt * 4096 + S * 8;
      *(u32x4*)(r1h + off) = ph;
      *(u32x4*)(r1l + off) = pl;
    }
  }
}

// ---------------------------------------------------------------------------
// K2: router. 512 blocks x 256 thr, 64 tokens/block. Layer-1 via split-fp16
// MFMA (3 products, fp32 acc). A-images: Ahi/Alo 32 KB each in a 64 KB smem
// union; rh (64x132 fp32, 33 KB) reuses the union after the k-loop.
// ---------------------------------------------------------------------------
__global__ __launch_bounds__(256) void router_kernel(
    const float* __restrict__ feat, const _Float16* __restrict__ r1h,
    const _Float16* __restrict__ r1l, const float* __restrict__ rb1,
    const float* __restrict__ rw2, const float* __restrict__ rb2,
    int* __restrict__ counts, int* __restrict__ list,
    float* __restrict__ wA) {
  __shared__ __align__(16) char smem[65536];         // Ahi|Alo, then rh
  __shared__ float plg[64 * 25];                     // partial logits
  __shared__ int lcnt[15], gbase[15];
  _Float16* Ahi = (_Float16*)smem;                   // 32 KB [kt8][rt4][64][8]
  _Float16* Alo = (_Float16*)(smem + 32768);         // 32 KB
  float* rh = (float*)smem;                          // reused after k-loop

  int tid = threadIdx.x;
  int wv = tid >> 6, L = tid & 63, m = L & 15, q = L >> 4;
  int tok0 = blockIdx.x * 64;

  // stage x: split fp32 -> (hi, lo*2048) fp16 A-frag images
  {
    int row = tid >> 2, seg = tid & 3;
    int rt = row >> 4, mm = row & 15;
    const float4* src = (const float4*)(feat + (size_t)(tok0 + row) * 256 + seg * 64);
    #pragma unroll
    for (int i = 0; i < 8; ++i) {
      float4 a = src[2 * i], b = src[2 * i + 1];
      u32x4 ph, pl;
      unsigned h0, l0;
      split_pair(a.x, a.y, h0, l0); ph[0] = h0; pl[0] = l0;
      split_pair(a.z, a.w, h0, l0); ph[1] = h0; pl[1] = l0;
      split_pair(b.x, b.y, h0, l0); ph[2] = h0; pl[2] = l0;
      split_pair(b.z, b.w, h0, l0); ph[3] = h0; pl[3] = l0;
      int k = seg * 64 + i * 8;
      int off = (((k >> 5) * 4 + rt) * 64 + ((k >> 3) & 3) * 16 + mm) * 8;
      *(u32x4*)(Ahi + off) = ph;
      *(u32x4*)(Alo + off) = pl;
    }
  }
  if (tid < 15) lcnt[tid] = 0;

  auto ldH = [&](int kt, int ct) -> f16x8 {
    return *(const f16x8*)(r1h + ((kt * 8 + wv * 2 + ct) * 64 + L) * 8);
  };
  auto ldL = [&](int kt, int ct) -> f16x8 {
    return *(const f16x8*)(r1l + ((kt * 8 + wv * 2 + ct) * 64 + L) * 8);
  };
  f16x8 bch[2], bcl[2];
  #pragma unroll
  for (int ct = 0; ct < 2; ++ct) { bch[ct] = ldH(0, ct); bcl[ct] = ldL(0, ct); }
  __syncthreads();                      // A images staged

  f32x4 ach[4][2], acm[4][2];
  #pragma unroll
  for (int ct = 0; ct < 2; ++ct) {
    float bv = rb1[wv * 32 + ct * 16 + m];
    #pragma unroll
    for (int rt = 0; rt < 4; ++rt) {
      ach[rt][ct][0] = bv; ach[rt][ct][1] = bv;
      ach[rt][ct][2] = bv; ach[rt][ct][3] = bv;
      acm[rt][ct][0] = 0.f; acm[rt][ct][1] = 0.f;
      acm[rt][ct][2] = 0.f; acm[rt][ct][3] = 0.f;
    }
  }
  #pragma unroll
  for (int kt = 0; kt < 8; ++kt) {
    f16x8 bnh[2], bnl[2];
    if (kt < 7) {
      #pragma unroll
      for (int ct = 0; ct < 2; ++ct) { bnh[ct] = ldH(kt + 1, ct); bnl[ct] = ldL(kt + 1, ct); }
    }
    f16x8 ah[4], al[4];
    #pragma unroll
    for (int rt = 0; rt < 4; ++rt) {
      ah[rt] = *(const f16x8*)(Ahi + ((kt * 4 + rt) * 64 + L) * 8);
      al[rt] = *(const f16x8*)(Alo + ((kt * 4 + rt) * 64 + L) * 8);
    }
    #pragma unroll
    for (int rt = 0; rt < 4; ++rt)
      #pragma unroll
      for (int ct = 0; ct < 2; ++ct)
        ach[rt][ct] = __builtin_amdgcn_mfma_f32_16x16x32_f16(
            ah[rt], bch[ct], ach[rt][ct], 0, 0, 0);
    #pragma unroll
    for (int rt = 0; rt < 4; ++rt)
      #pragma unroll
      for (int ct = 0; ct < 2; ++ct) {
        acm[rt][ct] = __builtin_amdgcn_mfma_f32_16x16x32_f16(
            ah[rt], bcl[ct], acm[rt][ct], 0, 0, 0);
        acm[rt][ct] = __builtin_amdgcn_mfma_f32_16x16x32_f16(
            al[rt], bch[ct], acm[rt][ct], 0, 0, 0);
      }
    if (kt < 7) {
      #pragma unroll
      for (int ct = 0; ct < 2; ++ct) { bch[ct] = bnh[ct]; bcl[ct] = bnl[ct]; }
    }
  }
  __syncthreads();                      // all A reads done; reuse smem as rh

  #pragma unroll
  for (int rt = 0; rt < 4; ++rt)
    #pragma unroll
    for (int ct = 0; ct < 2; ++ct)
      #pragma unroll
      for (int r = 0; r < 4; ++r) {
        float v = ach[rt][ct][r] + acm[rt][ct][r] * (1.f / 2048.f);
        int row = rt * 16 + q * 4 + r, h = wv * 32 + ct * 16 + m;
        rh[row * 132 + h] = fmaxf(v, 0.f);
      }
  __syncthreads();

  // layer 2: 4 threads per token, 32 h each
  {
    int t = tid >> 2, sub = tid & 3;
    float lgp[E_EXP] = {0.f, 0.f, 0.f, 0.f, 0.f, 0.f};
    #pragma unroll
    for (int c = 0; c < 8; ++c) {
      int c4 = sub * 8 + c;
      float4 xv = *(const float4*)(rh + t * 132 + c4 * 4);
      #pragma unroll
      for (int j = 0; j < 4; ++j) {
        float xj = (j == 0) ? xv.x : (j == 1) ? xv.y : (j == 2) ? xv.z : xv.w;
        const float* wr = rw2 + (c4 * 4 + j) * E_EXP;
        #pragma unroll
        for (int e2 = 0; e2 < E_EXP; ++e2)
          lgp[e2] = fmaf(xj, wr[e2], lgp[e2]);
      }
    }
    float* pp = plg + t * 25 + sub * 6;
    #pragma unroll
    for (int e2 = 0; e2 < E_EXP; ++e2) pp[e2] = lgp[e2];
  }
  __syncthreads();

  int pid = 0, loc = 0, token = 0;
  float wa = 0.f;
  if (tid < 64) {
    token = tok0 + tid;
    float p[E_EXP];
    float mx = -1e30f;
    #pragma unroll
    for (int i = 0; i < E_EXP; ++i) {
      p[i] = rb2[i] + plg[tid * 25 + i] + plg[tid * 25 + 6 + i] +
             plg[tid * 25 + 12 + i] + plg[tid * 25 + 18 + i];
      mx = fmaxf(mx, p[i]);
    }
    float sum = 0.f;
    #pragma unroll
    for (int i = 0; i < E_EXP; ++i) { p[i] = expf(p[i] - mx); sum += p[i]; }
    float inv = 1.f / sum;
    #pragma unroll
    for (int i = 0; i < E_EXP; ++i) p[i] *= inv;
    float b1v = p[0]; int sel0 = 0;
    #pragma unroll
    for (int i = 1; i < E_EXP; ++i) if (p[i] > b1v) { b1v = p[i]; sel0 = i; }
    float b2v = -1.f; int sel1 = 0;
    #pragma unroll
    for (int i = 0; i < E_EXP; ++i)
      if (i != sel0 && p[i] > b2v) { b2v = p[i]; sel1 = i; }
    float r = expf(b2v - b1v);          // softmax over the two top probs
    float sw0 = 1.f / (1.f + r);
    float sw1 = r / (1.f + r);
    int a = sel0 < sel1 ? sel0 : sel1;
    int b = sel0 < sel1 ? sel1 : sel0;
    wa = (sel0 < sel1) ? sw0 : sw1;     // weight of lower-index expert
    pid = b * (b - 1) / 2 + a;
    loc = atomicAdd(&lcnt[pid], 1);
  }
  __syncthreads();
  if (tid < 15) gbase[tid] = atomicAdd(&counts[tid], lcnt[tid]);
  __syncthreads();
  if (tid < 64) {
    int p0 = gbase[pid] + loc;
    list[pid * N_TOK + p0] = token;
    wA[pid * N_TOK + p0] = wa;
  }
}

// ---------------------------------------------------------------------------
// K3: pair-fused grouped GEMM. Block = 256 thr (4 waves), 32 tokens/block,
// one expert PAIR, two passes. A (acts) in 16 KB frag LDS; B (weights)
// global->VGPR with DEPTH-2 prefetch over the flat 48-step schedule.
// Output rows stored exactly once (f32x4, predicated). No atomics.
// ---------------------------------------------------------------------------
__global__ __launch_bounds__(256) void expert_kernel(
    const float* __restrict__ feat, const _Float16* __restrict__ wt,
    const float* __restrict__ eb1, const float* __restrict__ eb2,
    const float* __restrict__ eb3, const int* __restrict__ counts,
    const int* __restrict__ list, const float* __restrict__ wA,
    float* __restrict__ out) {
  __shared__ __align__(16) _Float16 Ah[8192];   // [kt=8][rt=2][64][8], 16 KB
  __shared__ int   toks[32];
  __shared__ float wgA[32];

  const int loT[15] = {0,0,1,0,1,2,0,1,2,3,0,1,2,3,4};
  const int hiT[15] = {1,2,2,3,3,3,4,4,4,4,5,5,5,5,5};

  int bid = blockIdx.x;
  int pid = 0, tile = 0, cnt = 0, cum = 0;
  #pragma unroll
  for (int i = 0; i < 15; ++i) {
    int ci = counts[i];
    int nt = (ci + 31) >> 5;
    bool hit = (bid >= cum) && (bid < cum + nt);
    if (hit) { pid = i; tile = bid - cum; cnt = ci; }
    cum += nt;
  }
  if (bid >= cum) return;
  int base = tile * 32;
  int eLo = loT[pid], eHi = hiT[pid];

  int tid = threadIdx.x;
  int wv = tid >> 6, L = tid & 63, m = L & 15, q = L >> 4;
  int wcol = wv * 64;

  if (tid < 32) {
    int idx = base + tid;
    int tk = 0; float a = 0.f;
    if (idx < cnt) { tk = list[pid * N_TOK + idx]; a = wA[pid * N_TOK + idx]; }
    toks[tid] = tk; wgA[tid] = a;
  }

  // flat step s = pass*24 + l*8 + kt; B frag loader (depth-2 prefetch)
  auto ldBs = [&](int s, int ct) -> f16x8 {
    int ee = (s >= 24) ? eHi : eLo;
    int ss = (s >= 24) ? s - 24 : s;
    return *(const f16x8*)(wt + ((size_t)ee * 24 + ss) * 8192 +
                           ((wv * 4 + ct) * 64 + L) * 8);
  };
  f16x8 bc[4], bn[4];
  #pragma unroll
  for (int ct = 0; ct < 4; ++ct) { bc[ct] = ldBs(0, ct); bn[ct] = ldBs(1, ct); }
  __syncthreads();                      // toks visible

  f32x4 acc[2][4], accS[2][4];

  #pragma unroll
  for (int pass = 0; pass < 2; ++pass) {
    int e = pass ? eHi : eLo;
    if (pass) __syncthreads();          // pass-0 layer-3 A reads done

    // stage A: gather 32 token rows fp32 -> fp16 frag image
    {
      int row = tid >> 3, seg = tid & 7;
      int rt = row >> 4, mm = row & 15;
      const float4* src = (const float4*)(feat + (size_t)toks[row] * 256 + seg * 32);
      #pragma unroll
      for (int i = 0; i < 4; ++i) {
        float4 a = src[2 * i], b = src[2 * i + 1];
        u32x4 pk;
        pk[0] = pack_f16x2(a.x, a.y);
        pk[1] = pack_f16x2(a.z, a.w);
        pk[2] = pack_f16x2(b.x, b.y);
        pk[3] = pack_f16x2(b.z, b.w);
        int k = seg * 32 + i * 8;
        int off = (((k >> 5) * 2 + rt) * 64 + ((k >> 3) & 3) * 16 + mm) * 8;
        *(u32x4*)(Ah + off) = pk;
      }
    }
    __syncthreads();

    const float* bias[3] = {eb1 + e * 256, eb2 + e * 256, eb3 + e * 256};

    #pragma unroll
    for (int l = 0; l < 3; ++l) {
      #pragma unroll
      for (int ct = 0; ct < 4; ++ct) {
        float bv = bias[l][wcol + ct * 16 + m];
        #pragma unroll
        for (int rt = 0; rt < 2; ++rt) {
          acc[rt][ct][0] = bv; acc[rt][ct][1] = bv;
          acc[rt][ct][2] = bv; acc[rt][ct][3] = bv;
        }
      }
      #pragma unroll
      for (int kt = 0; kt < 8; ++kt) {
        int s = pass * 24 + l * 8 + kt;
        int sp = (s + 2 <= 47) ? s + 2 : 47;
        f16x8 bn2[4];
        #pragma unroll
        for (int ct = 0; ct < 4; ++ct) bn2[ct] = ldBs(sp, ct);
        f16x8 af[2];
        #pragma unroll
        for (int rt = 0; rt < 2; ++rt)
          af[rt] = *(const f16x8*)(Ah + ((kt * 2 + rt) * 64 + L) * 8);
        #pragma unroll
        for (int rt = 0; rt < 2; ++rt)
          #pragma unroll
          for (int ct = 0; ct < 4; ++ct)
            acc[rt][ct] = __builtin_amdgcn_mfma_f32_16x16x32_f16(
                af[rt], bc[ct], acc[rt][ct], 0, 0, 0);
        #pragma unroll
        for (int ct = 0; ct < 4; ++ct) { bc[ct] = bn[ct]; bn[ct] = bn2[ct]; }
      }
      if (l < 2) {
        __syncthreads();                // all A reads done before overwrite
        int i = m & 3;
        bool s1 = (i & 2) != 0, s2 = (i & 1) != 0;
        #pragma unroll
        for (int rt = 0; rt < 2; ++rt) {
          #pragma unroll
          for (int ct = 0; ct < 4; ++ct) {
            float x0 = acc[rt][ct][0], x1 = acc[rt][ct][1];
            float x2 = acc[rt][ct][2], x3 = acc[rt][ct][3];
            float t0 = __shfl_xor(x2, 2), t1 = __shfl_xor(x3, 2);
            float t2 = __shfl_xor(x0, 2), t3 = __shfl_xor(x1, 2);
            x0 = s1 ? t0 : x0;  x1 = s1 ? t1 : x1;
            x2 = s1 ? x2 : t2;  x3 = s1 ? x3 : t3;
            float u0 = __shfl_xor(x1, 1), u1 = __shfl_xor(x0, 1);
            float u2 = __shfl_xor(x3, 1), u3 = __shfl_xor(x2, 1);
            x0 = s2 ? u0 : x0;  x1 = s2 ? x1 : u1;
            x2 = s2 ? u2 : x2;  x3 = s2 ? x3 : u3;
            uint2 pk;
            pk.x = pack_f16x2(fmaxf(x0, 0.f), fmaxf(x1, 0.f));
            pk.y = pack_f16x2(fmaxf(x2, 0.f), fmaxf(x3, 0.f));
            int n0 = wcol + ct * 16 + (m & ~3);
            int m2 = q * 4 + i;
            int off = (((n0 >> 5) * 2 + rt) * 64 + ((n0 >> 3) & 3) * 16 + m2) * 8 +
                      (n0 & 7);
            *(uint2*)(Ah + off) = pk;
          }
        }
        __syncthreads();
      }
    }

    if (pass == 0) {
      #pragma unroll
      for (int rt = 0; rt < 2; ++rt)
        #pragma unroll
        for (int r = 0; r < 4; ++r) {
          float wa = wgA[rt * 16 + q * 4 + r];
          #pragma unroll
          for (int ct = 0; ct < 4; ++ct)
            accS[rt][ct][r] = acc[rt][ct][r] * wa;
        }
    } else {
      #pragma unroll
      for (int rt = 0; rt < 2; ++rt)
        #pragma unroll
        for (int r = 0; r < 4; ++r) {
          float wb = 1.f - wgA[rt * 16 + q * 4 + r];
          #pragma unroll
          for (int ct = 0; ct < 4; ++ct)
            acc[rt][ct][r] = accS[rt][ct][r] + acc[rt][ct][r] * wb;
        }
    }
  }

  // final DPP transpose + predicated f32x4 stores (each row exactly once)
  {
    int i = m & 3;
    bool s1 = (i & 2) != 0, s2 = (i & 1) != 0;
    #pragma unroll
    for (int rt = 0; rt < 2; ++rt) {
      int row = rt * 16 + q * 4 + i;
      bool valid = (base + row) < cnt;
      #pragma unroll
      for (int ct = 0; ct < 4; ++ct) {
        float x0 = acc[rt][ct][0], x1 = acc[rt][ct][1];
        float x2 = acc[rt][ct][2], x3 = acc[rt][ct][3];
        float t0 = __shfl_xor(x2, 2), t1 = __shfl_xor(x3, 2);
        float t2 = __shfl_xor(x0, 2), t3 = __shfl_xor(x1, 2);
        x0 = s1 ? t0 : x0;  x1 = s1 ? t1 : x1;
        x2 = s1 ? x2 : t2;  x3 = s1 ? x3 : t3;
        float u0 = __shfl_xor(x1, 1), u1 = __shfl_xor(x0, 1);
        float u2 = __shfl_xor(x3, 1), u3 = __shfl_xor(x2, 1);
        x0 = s2 ? u0 : x0;  x1 = s2 ? x1 : u1;
        x2 = s2 ? u2 : x2;  x3 = s2 ? x3 : u3;
        if (valid) {
          float4 v = make_float4(x0, x1, x2, x3);
          *(float4*)(out + (size_t)toks[row] * 256 + wcol + ct * 16 + (m & ~3)) = v;
        }
      }
    }
  }
}

extern "C" void kernel_launch(void* const* d_in, const int* in_sizes, int n_in,
                              void* d_out, int out_size, void* d_ws, size_t ws_size,
                              hipStream_t stream) {
  const float* feat = (const float*)d_in[0];
  const float* rw1  = (const float*)d_in[1];
  const float* rb1  = (const float*)d_in[2];
  const float* rw2  = (const float*)d_in[3];
  const float* rb2  = (const float*)d_in[4];
  const float* ew1  = (const float*)d_in[5];
  const float* eb1  = (const float*)d_in[6];
  const float* ew2  = (const float*)d_in[7];
  const float* eb2  = (const float*)d_in[8];
  const float* ew3  = (const float*)d_in[9];
  const float* eb3  = (const float*)d_in[10];
  float* out = (float*)d_out;

  char* ws = (char*)d_ws;
  int*      counts = (int*)(ws);
  int*      list   = (int*)(ws + WS_LIST);
  float*    wA     = (float*)(ws + WS_WA);
  _Float16* wt     = (_Float16*)(ws + WS_WT);
  _Float16* r1h    = (_Float16*)(ws + WS_R1H);
  _Float16* r1l    = (_Float16*)(ws + WS_R1L);

  convert_w_kernel<<<152, 256, 0, stream>>>(ew1, ew2, ew3, rw1, wt, r1h, r1l,
                                            counts);
  router_kernel<<<N_TOK / 64, 256, 0, stream>>>(feat, r1h, r1l, rb1, rw2, rb2,
                                                counts, list, wA);
  // 32768 tokens -> <=1024 full tiles + <=15 ragged: 1039 blocks covers all.
  expert_kernel<<<1039, 256, 0, stream>>>(
      feat, wt, eb1, eb2, eb3, counts, list, wA, out);
}